// Round 8
// baseline (124.234 us; speedup 1.0000x reference)
//
#include <hip/hip_runtime.h>

#define B 4
#define C 128
#define H 128
#define W 128
#define HW (H * W)
#define KK 9
#define MID 25

#define SPATIAL_BLKS (HW / 256)   // 64 spatial blocks per batch (256 px each)

// native clang vector type: __builtin_nontemporal_store rejects HIP_vector_type
typedef float nat_f4 __attribute__((ext_vector_type(4)));

// Workspace layout (floats):
//   [0, 512)        xm      (B*C)   per-channel means
//   [8192, 598016)  S       (B*KK*HW) spatial filter
#define WS_XM 0
#define WS_S  8192

// K1: block-specialized fused kernel. grid (SPATIAL_BLKS + C, B), block 256.
//  - blocks [0, SPATIAL_BLKS): spatial filter sigmoid(x . Ws + bs).
//    Each lane owns 4 consecutive pixels (float4 loads = 1KB/wave-instr);
//    4 waves split channels (32 each), float4 LDS cross-wave reduce.
//  - blocks [SPATIAL_BLKS, ..+C): per-(b,c)-plane mean (x re-read is L3-served;
//    R5 showed in-loop cross-lane reduction is worse).
__global__ __launch_bounds__(256) void k_ms(
    const float* __restrict__ x, const float* __restrict__ Ws,
    const float* __restrict__ bs, float* __restrict__ xm,
    float* __restrict__ S)
{
    __shared__ float4 red4[3 * KK * 64];   // 27.6 KB
    __shared__ float redm[4];
    const int b = blockIdx.y;

    if (blockIdx.x >= SPATIAL_BLKS) {
        // ---- mean path ----
        const int c = blockIdx.x - SPATIAL_BLKS;
        const float4* plane = (const float4*)(x + ((size_t)b * C + c) * HW);
        float s = 0.0f;
#pragma unroll
        for (int i = 0; i < 16; ++i) {
            float4 v = plane[i * 256 + threadIdx.x];
            s += (v.x + v.y) + (v.z + v.w);
        }
#pragma unroll
        for (int off = 32; off > 0; off >>= 1) s += __shfl_down(s, off, 64);
        if ((threadIdx.x & 63) == 0) redm[threadIdx.x >> 6] = s;
        __syncthreads();
        if (threadIdx.x == 0)
            xm[b * C + c] = ((redm[0] + redm[1]) + (redm[2] + redm[3])) * (1.0f / HW);
        return;
    }

    // ---- spatial path: 256 px per block, lane owns 4 px ----
    const int lane = threadIdx.x & 63;
    const int wave = threadIdx.x >> 6;
    const int p0 = blockIdx.x * 256 + lane * 4;
    const float4* xb = (const float4*)(x + (size_t)b * C * HW + p0);

    float4 acc[KK];
#pragma unroll
    for (int k = 0; k < KK; ++k) {
        const float bk = (wave == 0) ? bs[k] : 0.0f;
        acc[k] = make_float4(bk, bk, bk, bk);
    }

    const int cbase = wave * 32;
#pragma unroll
    for (int i = 0; i < 32; ++i) {
        const int c = cbase + i;                  // wave-uniform -> scalar Ws loads
        float4 v = xb[(size_t)c * (HW / 4)];
#pragma unroll
        for (int k = 0; k < KK; ++k) {
            const float wk = Ws[k * C + c];
            acc[k].x = fmaf(v.x, wk, acc[k].x);
            acc[k].y = fmaf(v.y, wk, acc[k].y);
            acc[k].z = fmaf(v.z, wk, acc[k].z);
            acc[k].w = fmaf(v.w, wk, acc[k].w);
        }
    }

    if (wave > 0) {
#pragma unroll
        for (int k = 0; k < KK; ++k)
            red4[((wave - 1) * KK + k) * 64 + lane] = acc[k];
    }
    __syncthreads();
    if (wave == 0) {
#pragma unroll
        for (int k = 0; k < KK; ++k) {
            float4 a = acc[k];
            float4 r0 = red4[(0 * KK + k) * 64 + lane];
            float4 r1 = red4[(1 * KK + k) * 64 + lane];
            float4 r2 = red4[(2 * KK + k) * 64 + lane];
            a.x += (r0.x + r1.x) + r2.x;
            a.y += (r0.y + r1.y) + r2.y;
            a.z += (r0.z + r1.z) + r2.z;
            a.w += (r0.w + r1.w) + r2.w;
            float4 sg;
            sg.x = 1.0f / (1.0f + __expf(-a.x));
            sg.y = 1.0f / (1.0f + __expf(-a.y));
            sg.z = 1.0f / (1.0f + __expf(-a.z));
            sg.w = 1.0f / (1.0f + __expf(-a.w));
            *(float4*)(S + ((size_t)(b * KK + k)) * HW + p0) = sg;
        }
    }
}

// K3: dynamic 3x3 conv with fused channel-MLP preamble.
// Preamble parallelized: hid's 25x128 dot products split into 10 column
// segments (250 threads) + LDS reduce — no serial 128-FMA chain.
// Conv: each thread owns 4 consecutive pixels. grid (HW/1024, B, 16),
// pixel-block fastest (16 S-sharers are 64 apart = same XCD -> L2 reuse).
__global__ __launch_bounds__(256) void k_conv(
    const float* __restrict__ x, const float* __restrict__ S,
    const float* __restrict__ xm,
    const float* __restrict__ W1, const float* __restrict__ b1,
    const float* __restrict__ W2, const float* __restrict__ b2,
    float* __restrict__ out)
{
    const int tid = threadIdx.x;
    const int b = blockIdx.y;
    const int c0 = blockIdx.z * (C / 16);

    // ---- MLP preamble: ch[c0..c0+8) x 9 into LDS ----
    __shared__ float xmean[C];
    __shared__ float hpart[MID * 10];
    __shared__ float hid[MID];
    __shared__ float chs[(C / 16) * KK];   // 72
    if (tid < C) xmean[tid] = xm[b * C + tid];
    __syncthreads();
    if (tid < MID * 10) {
        const int m = tid / 10, seg = tid % 10;
        const int cb = seg * 13, ce = (cb + 13 < C) ? cb + 13 : C;
        float a = 0.0f;
        for (int c = cb; c < ce; ++c)
            a = fmaf(xmean[c], W1[m * C + c], a);
        hpart[tid] = a;
    }
    __syncthreads();
    if (tid < MID) {
        float a = b1[tid];
#pragma unroll
        for (int s = 0; s < 10; ++s) a += hpart[tid * 10 + s];
        hid[tid] = fmaxf(a, 0.0f);
    }
    __syncthreads();
    if (tid < (C / 16) * KK) {
        const int o = c0 * KK + tid;
        float a = b2[o];
#pragma unroll
        for (int m = 0; m < MID; ++m)
            a = fmaf(hid[m], W2[o * MID + m], a);
        chs[tid] = 1.0f / (1.0f + __expf(-a));
    }
    __syncthreads();

    // ---- conv ----
    const int p0 = (blockIdx.x * 256 + tid) * 4;
    const int h = p0 >> 7;          // /W
    const int w0 = p0 & (W - 1);    // multiple of 4

    // 9 per-pixel spatial-filter vectors; fold row/col tap validity into them.
    float4 sv[KK];
    const float* Sb = S + (size_t)b * KK * HW + p0;
#pragma unroll
    for (int k = 0; k < KK; ++k) {
        const int di = k / 3 - 1, dj = k % 3 - 1;
        const int hh = h + di;
        float4 s4 = *(const float4*)(Sb + (size_t)k * HW);
        if (hh < 0 || hh >= H) s4 = make_float4(0.f, 0.f, 0.f, 0.f);
        if (dj == -1 && w0 == 0)     s4.x = 0.f;   // col -1
        if (dj == +1 && w0 == W - 4) s4.w = 0.f;   // col W
        sv[k] = s4;
    }

    const int r0 = max(h - 1, 0), r2 = min(h + 1, H - 1);
    const int rowoff[3] = { r0 * W + w0, h * W + w0, r2 * W + w0 };
    const int loff = (w0 > 0) ? -1 : 0;       // masked by sv when w0==0
    const int roff = (w0 < W - 4) ? 4 : 0;    // masked by sv when w0==W-4

    const float* xb = x + (size_t)b * C * HW;
    float* ob = out + (size_t)b * C * HW + p0;

    for (int ci = 0; ci < C / 16; ++ci) {
        const int c = c0 + ci;
        const float* xc = xb + (size_t)c * HW;
        float4 Cx[3];
        float  Lw[3], Rx[3];
#pragma unroll
        for (int r = 0; r < 3; ++r) {
            const float* bp = xc + rowoff[r];
            Cx[r] = *(const float4*)bp;
            Lw[r] = bp[loff];
            Rx[r] = bp[roff];
        }
        float4 a = make_float4(0.f, 0.f, 0.f, 0.f);
#pragma unroll
        for (int k = 0; k < KK; ++k) {
            const int r = k / 3, dj = k % 3 - 1;
            float4 t;
            if (dj == -1)     t = make_float4(Lw[r], Cx[r].x, Cx[r].y, Cx[r].z);
            else if (dj == 0) t = Cx[r];
            else              t = make_float4(Cx[r].y, Cx[r].z, Cx[r].w, Rx[r]);
            const float cf = chs[ci * KK + k];  // uniform -> LDS broadcast
            a.x = fmaf(t.x, sv[k].x * cf, a.x);
            a.y = fmaf(t.y, sv[k].y * cf, a.y);
            a.z = fmaf(t.z, sv[k].z * cf, a.z);
            a.w = fmaf(t.w, sv[k].w * cf, a.w);
        }
        // out is write-once/never-read: nontemporal store (native vec type)
        nat_f4 av = { a.x, a.y, a.z, a.w };
        __builtin_nontemporal_store(av, (nat_f4*)(ob + (size_t)c * HW));
    }
}

extern "C" void kernel_launch(void* const* d_in, const int* in_sizes, int n_in,
                              void* d_out, int out_size, void* d_ws, size_t ws_size,
                              hipStream_t stream) {
    (void)in_sizes; (void)n_in; (void)out_size; (void)ws_size;
    const float* x  = (const float*)d_in[0];
    const float* Ws = (const float*)d_in[1];
    const float* bs = (const float*)d_in[2];
    const float* W1 = (const float*)d_in[3];
    const float* b1 = (const float*)d_in[4];
    const float* W2 = (const float*)d_in[5];
    const float* b2 = (const float*)d_in[6];
    float* out = (float*)d_out;
    float* ws  = (float*)d_ws;

    float* xm = ws + WS_XM;
    float* S  = ws + WS_S;

    k_ms<<<dim3(SPATIAL_BLKS + C, B), 256, 0, stream>>>(x, Ws, bs, xm, S);
    k_conv<<<dim3(HW / 1024, B, 16), 256, 0, stream>>>(x, S, xm, W1, b1, W2, b2, out);
}

// Round 9
// 111.933 us; speedup vs baseline: 1.1099x; 1.1099x over previous
//
#include <hip/hip_runtime.h>

#define B 4
#define C 128
#define H 128
#define W 128
#define HW (H * W)
#define KK 9
#define MID 25

#define SPATIAL_BLKS (HW / 64)   // 256 spatial blocks per batch

// Workspace layout (floats):
//   [0, 512)        xm      (B*C)   per-channel means
//   [8192, 598016)  S       (B*KK*HW) spatial filter
#define WS_XM 0
#define WS_S  8192

// K1: block-specialized fused kernel (R6 form — measured best).
// grid (SPATIAL_BLKS + C, B), block 256.
//  - blocks [0, SPATIAL_BLKS): spatial filter sigmoid(x . Ws + bs).
//    4 waves split channels (32 each), fully unrolled, LDS cross-wave reduce.
//  - blocks [SPATIAL_BLKS, ..+C): per-(b,c)-plane mean (x re-read L3-served;
//    R5: in-loop cross-lane reduce regressed; R8: float4 spatial was neutral —
//    bytes-in-flight conserved, so vectorization bought nothing).
__global__ __launch_bounds__(256) void k_ms(
    const float* __restrict__ x, const float* __restrict__ Ws,
    const float* __restrict__ bs, float* __restrict__ xm,
    float* __restrict__ S)
{
    __shared__ float red[3 * KK * 64];
    const int b = blockIdx.y;

    if (blockIdx.x >= SPATIAL_BLKS) {
        // ---- mean path ----
        const int c = blockIdx.x - SPATIAL_BLKS;
        const float4* plane = (const float4*)(x + ((size_t)b * C + c) * HW);
        float s = 0.0f;
#pragma unroll
        for (int i = 0; i < 16; ++i) {
            float4 v = plane[i * 256 + threadIdx.x];
            s += (v.x + v.y) + (v.z + v.w);
        }
#pragma unroll
        for (int off = 32; off > 0; off >>= 1) s += __shfl_down(s, off, 64);
        if ((threadIdx.x & 63) == 0) red[threadIdx.x >> 6] = s;
        __syncthreads();
        if (threadIdx.x == 0)
            xm[b * C + c] = ((red[0] + red[1]) + (red[2] + red[3])) * (1.0f / HW);
        return;
    }

    // ---- spatial path ----
    const int lane = threadIdx.x & 63;
    const int wave = threadIdx.x >> 6;
    const int p = blockIdx.x * 64 + lane;
    const float* xb = x + (size_t)b * C * HW + p;

    float acc[KK];
#pragma unroll
    for (int k = 0; k < KK; ++k) acc[k] = (wave == 0) ? bs[k] : 0.0f;

    const int cbase = wave * 32;
#pragma unroll
    for (int i = 0; i < 32; ++i) {
        const int c = cbase + i;                 // wave-uniform -> scalar Ws loads
        float v = xb[(size_t)c * HW];
#pragma unroll
        for (int k = 0; k < KK; ++k)
            acc[k] = fmaf(v, Ws[k * C + c], acc[k]);
    }

    if (wave > 0) {
#pragma unroll
        for (int k = 0; k < KK; ++k)
            red[((wave - 1) * KK + k) * 64 + lane] = acc[k];
    }
    __syncthreads();
    if (wave == 0) {
#pragma unroll
        for (int k = 0; k < KK; ++k) {
            float a = acc[k] + red[(0 * KK + k) * 64 + lane]
                             + red[(1 * KK + k) * 64 + lane]
                             + red[(2 * KK + k) * 64 + lane];
            S[((size_t)(b * KK + k)) * HW + p] = 1.0f / (1.0f + __expf(-a));
        }
    }
}

// K3: dynamic 3x3 conv with fused channel-MLP preamble (R6 form) + NEW:
// edge taps via cross-lane shuffle instead of scalar VMEM loads.
// Each thread owns 4 consecutive pixels; lane t's left-edge value x[p0-1] is
// lane t-1's Cx.w, right-edge x[p0+4] is lane t+1's Cx.x. Each wave covers
// exactly 2 full rows, so every shuffle-boundary lane (0, 63, and the 31->32
// row crossing) is exactly a position already masked by sv -> safe.
// VMEM per channel drops 6 -> 4 (3 float4 loads + 1 store); 6 independent
// shuffles/channel go to the idle DS pipe (NOT R5's dependent butterfly).
__global__ __launch_bounds__(256) void k_conv(
    const float* __restrict__ x, const float* __restrict__ S,
    const float* __restrict__ xm,
    const float* __restrict__ W1, const float* __restrict__ b1,
    const float* __restrict__ W2, const float* __restrict__ b2,
    float* __restrict__ out)
{
    const int tid = threadIdx.x;
    const int b = blockIdx.y;
    const int c0 = blockIdx.z * (C / 16);

    // ---- MLP preamble: ch[c0..c0+8) x 9 into LDS ----
    __shared__ float xmean[C];
    __shared__ float hid[MID];
    __shared__ float chs[(C / 16) * KK];   // 72
    if (tid < C) xmean[tid] = xm[b * C + tid];
    __syncthreads();
    if (tid < MID) {
        float a = b1[tid];
#pragma unroll 8
        for (int c = 0; c < C; ++c)
            a = fmaf(xmean[c], W1[tid * C + c], a);
        hid[tid] = fmaxf(a, 0.0f);
    }
    __syncthreads();
    if (tid < (C / 16) * KK) {
        const int o = c0 * KK + tid;
        float a = b2[o];
#pragma unroll
        for (int m = 0; m < MID; ++m)
            a = fmaf(hid[m], W2[o * MID + m], a);
        chs[tid] = 1.0f / (1.0f + __expf(-a));
    }
    __syncthreads();

    // ---- conv ----
    const int p0 = (blockIdx.x * 256 + tid) * 4;
    const int h = p0 >> 7;          // /W
    const int w0 = p0 & (W - 1);    // multiple of 4

    // 9 per-pixel spatial-filter vectors; fold row/col tap validity into them.
    float4 sv[KK];
    const float* Sb = S + (size_t)b * KK * HW + p0;
#pragma unroll
    for (int k = 0; k < KK; ++k) {
        const int di = k / 3 - 1, dj = k % 3 - 1;
        const int hh = h + di;
        float4 s4 = *(const float4*)(Sb + (size_t)k * HW);
        if (hh < 0 || hh >= H) s4 = make_float4(0.f, 0.f, 0.f, 0.f);
        if (dj == -1 && w0 == 0)     s4.x = 0.f;   // col -1
        if (dj == +1 && w0 == W - 4) s4.w = 0.f;   // col W
        sv[k] = s4;
    }

    const int r0 = max(h - 1, 0), r2 = min(h + 1, H - 1);
    const int rowoff[3] = { r0 * W + w0, h * W + w0, r2 * W + w0 };

    const float* xb = x + (size_t)b * C * HW;
    float* ob = out + (size_t)b * C * HW + p0;

    for (int ci = 0; ci < C / 16; ++ci) {
        const int c = c0 + ci;
        const float* xc = xb + (size_t)c * HW;
        float4 Cx[3];
        float  Lw[3], Rx[3];
#pragma unroll
        for (int r = 0; r < 3; ++r)
            Cx[r] = *(const float4*)(xc + rowoff[r]);
#pragma unroll
        for (int r = 0; r < 3; ++r) {
            // neighbor-lane edge taps; boundary lanes are sv-masked
            Lw[r] = __shfl_up(Cx[r].w, 1, 64);
            Rx[r] = __shfl_down(Cx[r].x, 1, 64);
        }
        float4 a = make_float4(0.f, 0.f, 0.f, 0.f);
#pragma unroll
        for (int k = 0; k < KK; ++k) {
            const int r = k / 3, dj = k % 3 - 1;
            float4 t;
            if (dj == -1)     t = make_float4(Lw[r], Cx[r].x, Cx[r].y, Cx[r].z);
            else if (dj == 0) t = Cx[r];
            else              t = make_float4(Cx[r].y, Cx[r].z, Cx[r].w, Rx[r]);
            const float cf = chs[ci * KK + k];  // uniform -> LDS broadcast
            a.x = fmaf(t.x, sv[k].x * cf, a.x);
            a.y = fmaf(t.y, sv[k].y * cf, a.y);
            a.z = fmaf(t.z, sv[k].z * cf, a.z);
            a.w = fmaf(t.w, sv[k].w * cf, a.w);
        }
        *(float4*)(ob + (size_t)c * HW) = a;    // coalesced 16B store
    }
}

extern "C" void kernel_launch(void* const* d_in, const int* in_sizes, int n_in,
                              void* d_out, int out_size, void* d_ws, size_t ws_size,
                              hipStream_t stream) {
    (void)in_sizes; (void)n_in; (void)out_size; (void)ws_size;
    const float* x  = (const float*)d_in[0];
    const float* Ws = (const float*)d_in[1];
    const float* bs = (const float*)d_in[2];
    const float* W1 = (const float*)d_in[3];
    const float* b1 = (const float*)d_in[4];
    const float* W2 = (const float*)d_in[5];
    const float* b2 = (const float*)d_in[6];
    float* out = (float*)d_out;
    float* ws  = (float*)d_ws;

    float* xm = ws + WS_XM;
    float* S  = ws + WS_S;

    k_ms<<<dim3(SPATIAL_BLKS + C, B), 256, 0, stream>>>(x, Ws, bs, xm, S);
    k_conv<<<dim3(HW / 1024, B, 16), 256, 0, stream>>>(x, S, xm, W1, b1, W2, b2, out);
}